// Round 2
// 740.303 us; speedup vs baseline: 1.0111x; 1.0111x over previous
//
#include <hip/hip_runtime.h>

#define S_ 2048
#define D_ 1024
#define H_ 16
#define HD_ 64

typedef __attribute__((ext_vector_type(8))) short short8;
typedef __attribute__((ext_vector_type(4))) float floatx4;

#define MFMA16(a, b, c) __builtin_amdgcn_mfma_f32_16x16x32_bf16(a, b, c, 0, 0, 0)
#define EXP2 __builtin_amdgcn_exp2f

__device__ __forceinline__ unsigned short f2bf(float f) {
    union { float f; unsigned int u; } v; v.f = f;
    unsigned int r = v.u + 0x7FFFu + ((v.u >> 16) & 1u);  // RNE
    return (unsigned short)(r >> 16);
}

// async global->LDS, 16B per lane. LDS dest must be linear (base + lane*16).
__device__ __forceinline__ void gll16(const unsigned short* g, unsigned short* l) {
    __builtin_amdgcn_global_load_lds(
        (const __attribute__((address_space(1))) void*)g,
        (__attribute__((address_space(3))) void*)l, 16, 0, 0);
}

// ---------------- elementwise fp32 -> bf16 cast ----------------
__global__ __launch_bounds__(256) void cast_bf16(const float* __restrict__ in,
                                                 unsigned short* __restrict__ out, int n4) {
    int i = blockIdx.x * 256 + threadIdx.x;
    if (i < n4) {
        float4 v = ((const float4*)in)[i];
        ushort4 o;
        o.x = f2bf(v.x); o.y = f2bf(v.y); o.z = f2bf(v.z); o.w = f2bf(v.w);
        ((ushort4*)out)[i] = o;
    }
}

// ---------------- W [K][N] fp32 -> W^T [N][K] bf16 (64x64 LDS tiles) ----------------
__global__ __launch_bounds__(256) void transpose_cast(const float* __restrict__ W,
                                                      unsigned short* __restrict__ WT,
                                                      int K, int N) {
    __shared__ float tb[64][65];
    const int t = threadIdx.x;
    const int tr = t >> 4, tc = t & 15;
    const int n0 = blockIdx.x * 64, k0 = blockIdx.y * 64;
#pragma unroll
    for (int p = 0; p < 4; ++p) {
        const int r = p * 16 + tr;
        const float4 v = *(const float4*)&W[(size_t)(k0 + r) * N + n0 + tc * 4];
        tb[r][tc * 4 + 0] = v.x; tb[r][tc * 4 + 1] = v.y;
        tb[r][tc * 4 + 2] = v.z; tb[r][tc * 4 + 3] = v.w;
    }
    __syncthreads();
#pragma unroll
    for (int p = 0; p < 4; ++p) {
        const int rn = p * 16 + tr;
        ushort4 o;
        o.x = f2bf(tb[tc * 4 + 0][rn]); o.y = f2bf(tb[tc * 4 + 1][rn]);
        o.z = f2bf(tb[tc * 4 + 2][rn]); o.w = f2bf(tb[tc * 4 + 3][rn]);
        *(ushort4*)&WT[(size_t)(n0 + rn) * K + k0 + tc * 4] = o;
    }
}

// ---------------- bf16 MFMA GEMM: C[M][N] = A[M][K] * Bt[N][K]^T + bias ----------------
// 128x128 tile, BK=32, 4 waves (2x2). Double-buffered global_load_lds staging,
// ONE barrier per K-step. LDS granule-swizzled (g ^= (row>>1)&3) so ds_read_b128
// fragment reads are 2-way (free) instead of 8-way bank-conflicted.
__global__ __launch_bounds__(256) void gemm_bt(
    const unsigned short* __restrict__ A, const unsigned short* __restrict__ Bt,
    const float* __restrict__ bias, float* __restrict__ outp,
    unsigned short* __restrict__ qw, unsigned short* __restrict__ kw,
    unsigned short* __restrict__ vtw, int M, int N, int K, int mode)
{
    __shared__ unsigned short As[2][128 * 32];
    __shared__ unsigned short Bs[2][128 * 32];

    const int tid = threadIdx.x;
    const int w = tid >> 6, lane = tid & 63;
    const int l15 = lane & 15, qd = lane >> 4;
    const int wr = w >> 1, wc = w & 1;
    const int row0 = blockIdx.y * 128, col0 = blockIdx.x * 128;

    floatx4 acc[4][4];
#pragma unroll
    for (int i = 0; i < 4; ++i)
#pragma unroll
        for (int j = 0; j < 4; ++j) acc[i][j] = (floatx4){0.f, 0.f, 0.f, 0.f};

    // staging geometry: LDS granule L=(round*256+tid) <-> row=L>>2, part=L&3.
    // swizzled source granule = part ^ ((row>>1)&3)   (same for row and row+64)
    const int sr = tid >> 2;
    const int gs = (tid & 3) ^ ((tid >> 3) & 3);
    const unsigned short* Ab0 = A + (size_t)(row0 + sr) * K + gs * 8;
    const unsigned short* Ab1 = A + (size_t)(row0 + 64 + sr) * K + gs * 8;
    const unsigned short* Bb0 = Bt + (size_t)(col0 + sr) * K + gs * 8;
    const unsigned short* Bb1 = Bt + (size_t)(col0 + 64 + sr) * K + gs * 8;

    auto stage = [&](int bi, int k0) {
        gll16(Ab0 + k0, &As[bi][tid * 8]);
        gll16(Ab1 + k0, &As[bi][(256 + tid) * 8]);
        gll16(Bb0 + k0, &Bs[bi][tid * 8]);
        gll16(Bb1 + k0, &Bs[bi][(256 + tid) * 8]);
    };

    stage(0, 0);
    const int nk = K >> 5;
    for (int it = 0; it < nk; ++it) {
        __syncthreads();                       // tile `it` staged & visible
        if (it + 1 < nk) stage((it + 1) & 1, (it + 1) << 5);
        const unsigned short* Asb = As[it & 1];
        const unsigned short* Bsb = Bs[it & 1];
        short8 af[4], bfr[4];
#pragma unroll
        for (int mi = 0; mi < 4; ++mi) {
            const int ra = wr * 64 + mi * 16 + l15;
            af[mi] = *(const short8*)&Asb[ra * 32 + ((qd ^ ((ra >> 1) & 3)) << 3)];
        }
#pragma unroll
        for (int ni = 0; ni < 4; ++ni) {
            const int rb = wc * 64 + ni * 16 + l15;
            bfr[ni] = *(const short8*)&Bsb[rb * 32 + ((qd ^ ((rb >> 1) & 3)) << 3)];
        }
#pragma unroll
        for (int mi = 0; mi < 4; ++mi)
#pragma unroll
            for (int ni = 0; ni < 4; ++ni)
                acc[mi][ni] = MFMA16(af[mi], bfr[ni], acc[mi][ni]);
    }

#pragma unroll
    for (int mi = 0; mi < 4; ++mi)
#pragma unroll
        for (int ni = 0; ni < 4; ++ni) {
            const int col = col0 + wc * 64 + ni * 16 + l15;
            const float bv = bias[col];
#pragma unroll
            for (int r = 0; r < 4; ++r) {
                const int row = row0 + wr * 64 + mi * 16 + qd * 4 + r;
                const float v = acc[mi][ni][r] + bv;
                if (mode == 0) {
                    __builtin_nontemporal_store(v, &outp[(size_t)row * N + col]);
                } else {
                    const int region = col >> 10;
                    const int hh = (col >> 6) & 15;
                    const int dd = col & 63;
                    const int bb = row >> 11;
                    const int ss = row & 2047;
                    const unsigned short bvv = f2bf(v);
                    if (region == 0)
                        qw[((size_t)(bb * 16 + hh) * 2048 + ss) * 64 + dd] = bvv;
                    else if (region == 1)
                        kw[((size_t)(bb * 16 + hh) * 2048 + ss) * 64 + dd] = bvv;
                    else
                        vtw[((size_t)(bb * 16 + hh) * 64 + dd) * 2048 + ss] = bvv;
                }
            }
        }
}

// ---------------- MFMA attention: block per (b,h, 64-row q tile), two-pass ----------------
// Double-buffered global_load_lds K/V staging (1 barrier/tile in pass 1, 2 in pass 2),
// XOR-granule-swizzled linear LDS (2-way reads), exp2-domain softmax, nontemporal
// attn-prob stores issued after the Ps barrier so they drain a full phase later.
__global__ __launch_bounds__(256) void attn_mfma(
    const unsigned short* __restrict__ qg, const unsigned short* __restrict__ kg,
    const unsigned short* __restrict__ vtg, const float* __restrict__ mask,
    float* __restrict__ attnOut, unsigned short* __restrict__ ctxOut)
{
    __shared__ unsigned short Qb[64 * 64];
    __shared__ unsigned short Kb[2][64 * 64];
    __shared__ unsigned short Vb[2][64 * 64];
    __shared__ unsigned short Ps[64 * 80];
    __shared__ float maskS[2][64];

    const int tid = threadIdx.x;
    const int w = tid >> 6, lane = tid & 63;
    const int l15 = lane & 15, qd = lane >> 4;
    const int x = blockIdx.x;
    const int bh = x & 31;
    const int qt = 31 - (x >> 5);      // heavy tiles dispatch first
    const int b = bh >> 4, h = bh & 15;
    const size_t base = (size_t)bh * (S_ * HD_);
    const float SC = 0.18033688f;      // 0.125 * log2(e)

    // staging geometry: LDS granule L=(round*256+tid) <-> row=L>>3, part=L&7.
    // swizzled source granule = part ^ (row&7)   (same for row and row+32)
    const int sr = tid >> 3;
    const int sp = tid & 7;
    const int gsw = sp ^ (sr & 7);

    auto stageK = [&](int bi, int jt) {
        const unsigned short* gk = kg + base + (size_t)jt * 4096;
        gll16(gk + sr * 64 + gsw * 8, &Kb[bi][tid * 8]);
        gll16(gk + (sr + 32) * 64 + gsw * 8, &Kb[bi][(256 + tid) * 8]);
    };
    auto stageV = [&](int bi, int jt) {
        const unsigned short* gv = vtg + base + jt * 64;
        gll16(gv + (size_t)sr * S_ + gsw * 8, &Vb[bi][tid * 8]);
        gll16(gv + (size_t)(sr + 32) * S_ + gsw * 8, &Vb[bi][(256 + tid) * 8]);
    };

    // prologue: Q + K0 + mask0
    {
        const unsigned short* gq = qg + base + (size_t)qt * 4096;
        gll16(gq + sr * 64 + gsw * 8, &Qb[tid * 8]);
        gll16(gq + (sr + 32) * 64 + gsw * 8, &Qb[(256 + tid) * 8]);
    }
    stageK(0, 0);
    if (tid < 64) maskS[0][tid] = mask[b * S_ + tid];
    __syncthreads();

    const int qr = w * 16 + l15;
    const short8 aq0 = *(const short8*)&Qb[qr * 64 + ((qd ^ (qr & 7)) << 3)];
    const short8 aq1 = *(const short8*)&Qb[qr * 64 + (((4 + qd) ^ (qr & 7)) << 3)];

    const int qrow_base = qt * 64 + w * 16 + qd * 4;
    float m_i[4], l_i[4], rl[4];
#pragma unroll
    for (int r = 0; r < 4; ++r) { m_i[r] = -3e38f; l_i[r] = 0.f; }

    // ---- pass 1: softmax stats (1 barrier per tile) ----
    for (int jt = 0; jt <= qt; ++jt) {
        const int cb = jt & 1;
        if (jt < qt) {
            stageK(cb ^ 1, jt + 1);
            if (tid < 64) maskS[cb ^ 1][tid] = mask[b * S_ + (jt + 1) * 64 + tid];
        }
        float sv[4][4];
        bool mok[4];
        __builtin_amdgcn_s_setprio(1);
#pragma unroll
        for (int ni = 0; ni < 4; ++ni) {
            const int kr = ni * 16 + l15;
            const short8 bk0 = *(const short8*)&Kb[cb][kr * 64 + ((qd ^ (kr & 7)) << 3)];
            const short8 bk1 = *(const short8*)&Kb[cb][kr * 64 + (((4 + qd) ^ (kr & 7)) << 3)];
            floatx4 s = {0.f, 0.f, 0.f, 0.f};
            s = MFMA16(aq0, bk0, s);
            s = MFMA16(aq1, bk1, s);
#pragma unroll
            for (int r = 0; r < 4; ++r) sv[ni][r] = s[r] * SC;
            mok[ni] = (maskS[cb][kr] == 1.0f);
        }
        __builtin_amdgcn_s_setprio(0);
        const bool diag = (jt == qt);
#pragma unroll
        for (int r = 0; r < 4; ++r) {
            const int qrow = qrow_base + r;
            float svr[4], tm = -3e38f;
#pragma unroll
            for (int ni = 0; ni < 4; ++ni) {
                const bool ok = mok[ni] && (!diag || (jt * 64 + ni * 16 + l15 <= qrow));
                svr[ni] = ok ? sv[ni][r] : -3e38f;
                tm = fmaxf(tm, svr[ni]);
            }
            if (tm > -1e37f) {
                const float mn = fmaxf(m_i[r], tm);
                const float sum = EXP2(svr[0] - mn) + EXP2(svr[1] - mn) +
                                  EXP2(svr[2] - mn) + EXP2(svr[3] - mn);
                l_i[r] = l_i[r] * EXP2(m_i[r] - mn) + sum;
                m_i[r] = mn;
            }
        }
        __syncthreads();   // drains stage loads for tile jt+1; protects buffer reuse
    }

    // butterfly reduce over the 16 lanes sharing each row
#pragma unroll
    for (int r = 0; r < 4; ++r) {
        float m = m_i[r], l = l_i[r];
#pragma unroll
        for (int off = 1; off < 16; off <<= 1) {
            const float mo = __shfl_xor(m, off);
            const float lo = __shfl_xor(l, off);
            const float mn = fmaxf(m, mo);
            l = l * EXP2(m - mn) + lo * EXP2(mo - mn);
            m = mn;
        }
        m_i[r] = m;
        rl[r] = 1.0f / l;
    }

    // ---- pass 2: attn write + ctx ----
    stageK(0, 0);
    stageV(0, 0);
    if (tid < 64) maskS[0][tid] = mask[b * S_ + tid];

    floatx4 ctxa[4];
#pragma unroll
    for (int ni = 0; ni < 4; ++ni) ctxa[ni] = (floatx4){0.f, 0.f, 0.f, 0.f};
    float* attnBH = attnOut + (size_t)bh * S_ * S_;

    for (int jt = 0; jt < 32; ++jt) {
        if (jt <= qt) {
            const int cb = jt & 1;
            __syncthreads();               // K/V/mask tile jt ready
            if (jt < qt) {
                stageK(cb ^ 1, jt + 1);
                stageV(cb ^ 1, jt + 1);
                if (tid < 64) maskS[cb ^ 1][tid] = mask[b * S_ + (jt + 1) * 64 + tid];
            }
            float pm[4][4];
            bool mok[4];
            __builtin_amdgcn_s_setprio(1);
#pragma unroll
            for (int ni = 0; ni < 4; ++ni) {
                const int kr = ni * 16 + l15;
                const short8 bk0 = *(const short8*)&Kb[cb][kr * 64 + ((qd ^ (kr & 7)) << 3)];
                const short8 bk1 = *(const short8*)&Kb[cb][kr * 64 + (((4 + qd) ^ (kr & 7)) << 3)];
                floatx4 s = {0.f, 0.f, 0.f, 0.f};
                s = MFMA16(aq0, bk0, s);
                s = MFMA16(aq1, bk1, s);
#pragma unroll
                for (int r = 0; r < 4; ++r) pm[ni][r] = s[r] * SC;
                mok[ni] = (maskS[cb][kr] == 1.0f);
            }
            __builtin_amdgcn_s_setprio(0);
            const bool diag = (jt == qt);
#pragma unroll
            for (int ni = 0; ni < 4; ++ni)
#pragma unroll
                for (int r = 0; r < 4; ++r) {
                    const int qrow = qrow_base + r;
                    const bool ok = mok[ni] && (!diag || (jt * 64 + ni * 16 + l15 <= qrow));
                    const float p = ok ? EXP2(pm[ni][r] - m_i[r]) * rl[r] : 0.0f;
                    pm[ni][r] = p;
                    Ps[(w * 16 + qd * 4 + r) * 80 + ni * 16 + l15] = f2bf(p);
                }
            __syncthreads();               // Ps ready (also drains stage loads)
            // attn-prob stores: nontemporal (write-once 537 MB, keep out of L2),
            // issued here so PV below covers their latency before next barrier.
#pragma unroll
            for (int ni = 0; ni < 4; ++ni)
#pragma unroll
                for (int r = 0; r < 4; ++r)
                    __builtin_nontemporal_store(
                        pm[ni][r],
                        &attnBH[(size_t)(qrow_base + r) * S_ + jt * 64 + ni * 16 + l15]);
            __builtin_amdgcn_s_setprio(1);
#pragma unroll
            for (int kk = 0; kk < 2; ++kk) {
                const short8 ap = *(const short8*)&Ps[(w * 16 + l15) * 80 + kk * 32 + qd * 8];
#pragma unroll
                for (int ni = 0; ni < 4; ++ni) {
                    const int vr = ni * 16 + l15;
                    const short8 bv = *(const short8*)
                        &Vb[cb][vr * 64 + (((kk * 4 + qd) ^ (vr & 7)) << 3)];
                    ctxa[ni] = MFMA16(ap, bv, ctxa[ni]);
                }
            }
            __builtin_amdgcn_s_setprio(0);
        } else {
            const floatx4 z = {0.f, 0.f, 0.f, 0.f};
#pragma unroll
            for (int p = 0; p < 4; ++p) {
                const int c = p * 256 + tid;
                const int row = c >> 4, part = c & 15;
                __builtin_nontemporal_store(
                    z, (floatx4*)&attnBH[(size_t)(qt * 64 + row) * S_ + jt * 64 + part * 4]);
            }
        }
    }

    // ctx -> bf16 [B,S,D]
#pragma unroll
    for (int ni = 0; ni < 4; ++ni)
#pragma unroll
        for (int r = 0; r < 4; ++r) {
            const int qrow = qrow_base + r;
            ctxOut[((size_t)(b * S_ + qrow)) * D_ + h * 64 + ni * 16 + l15] =
                f2bf(ctxa[ni][r]);
        }
}

extern "C" void kernel_launch(void* const* d_in, const int* in_sizes, int n_in,
                              void* d_out, int out_size, void* d_ws, size_t ws_size,
                              hipStream_t stream) {
    const float* hidden = (const float*)d_in[0];
    const float* mask   = (const float*)d_in[1];
    const float* w_attn = (const float*)d_in[2];
    const float* b_attn = (const float*)d_in[3];
    const float* w_proj = (const float*)d_in[4];
    const float* b_proj = (const float*)d_in[5];

    float* out = (float*)d_out;
    float* attnOut = out + (size_t)2 * S_ * D_;

    unsigned short* ws = (unsigned short*)d_ws;
    const size_t E = (size_t)2 * S_ * D_;       // 4,194,304
    unsigned short* Xb   = ws;                  // [2*S, D]
    unsigned short* WaT  = Xb + E;              // [3D, D]
    unsigned short* WpT  = WaT + (size_t)3 * D_ * D_;  // [D, D]
    unsigned short* qw   = WpT + (size_t)D_ * D_;      // [B,H,S,HD]
    unsigned short* kw   = qw + E;
    unsigned short* vtw  = kw + E;              // [B,H,HD,S]
    unsigned short* ctxb = vtw + E;             // [2*S, D]

    dim3 blk(256);
    cast_bf16<<<dim3((int)(E / 4 / 256)), blk, 0, stream>>>(hidden, Xb, (int)(E / 4));
    transpose_cast<<<dim3(3 * D_ / 64, D_ / 64), blk, 0, stream>>>(w_attn, WaT, D_, 3 * D_);
    transpose_cast<<<dim3(D_ / 64, D_ / 64), blk, 0, stream>>>(w_proj, WpT, D_, D_);

    gemm_bt<<<dim3(3 * D_ / 128, 2 * S_ / 128), blk, 0, stream>>>(
        Xb, WaT, b_attn, nullptr, qw, kw, vtw, 2 * S_, 3 * D_, D_, 1);

    attn_mfma<<<dim3(2 * H_ * (S_ / 64)), blk, 0, stream>>>(
        qw, kw, vtw, mask, attnOut, ctxb);

    gemm_bt<<<dim3(D_ / 128, 2 * S_ / 128), blk, 0, stream>>>(
        ctxb, WpT, b_proj, out, nullptr, nullptr, nullptr, 2 * S_, D_, D_, 0);
}